// Round 6
// baseline (281.744 us; speedup 1.0000x reference)
//
#include <hip/hip_runtime.h>
#include <hip/hip_fp16.h>
#include <math.h>
#include <stdint.h>

#define HH 512
#define WW 512
#define NIMG 24
#define CCH 3
#define TAU 0.25f
#define TVEPS 2e-4f
#define NUMEL 262144.0f
#define NITER 10

// ws layout (256 MiB):
//   byte 0     : sc — 2 slots x 96 floats, slot s at sc+96*s:
//                [0..23]=E_prev, [24..47]=E_init, int[48..71]=done, int[72..95]=last_k
//   byte 4096  : pd [2][NIMG][64]  (slot = it&1; stepN writes 32 entries/image)
//   byte 16384 : pn [2][NIMG][64]  (slot 0 also holds step0's 64 entries)
//   byte 32768 : imgh (__half, 24*512*512)
//   byte 12615680 : ptA (uint32 packed half2)
//   byte 37781504 : ptB

__device__ __forceinline__ float2 h2f(uint32_t v) {
    __half2 h; *reinterpret_cast<uint32_t*>(&h) = v;
    return __half22float2(h);
}
__device__ __forceinline__ uint32_t f2h2(float a, float b) {
    __half2 h = __floats2half2_rn(a, b);
    return *reinterpret_cast<uint32_t*>(&h);
}
__device__ __forceinline__ void h4_to_f(uint2 hv, float* f) {
    float2 a = h2f(hv.x), b = h2f(hv.y);
    f[0] = a.x; f[1] = a.y; f[2] = b.x; f[3] = b.y;
}

__device__ __forceinline__ void block_reduce_store(float v0, float v1,
                                                   float* p0, float* p1, int tid) {
    for (int off = 32; off > 0; off >>= 1) {
        v0 += __shfl_down(v0, off, 64);
        v1 += __shfl_down(v1, off, 64);
    }
    __shared__ float sr[2][4];
    int wave = tid >> 6, lane = tid & 63;
    if (lane == 0) { sr[0][wave] = v0; sr[1][wave] = v1; }
    __syncthreads();
    if (tid == 0) {
        *p0 = (sr[0][0] + sr[0][1]) + (sr[0][2] + sr[0][3]);
        *p1 = (sr[1][0] + sr[1][1]) + (sr[1][2] + sr[1][3]);
    }
}

__device__ __forceinline__ void block_reduce_store1(float v, float* p, int tid) {
    for (int off = 32; off > 0; off >>= 1) v += __shfl_down(v, off, 64);
    __shared__ float sr[4];
    if ((tid & 63) == 0) sr[tid >> 6] = v;
    __syncthreads();
    if (tid == 0) *p = (sr[0] + sr[1]) + (sr[2] + sr[3]);
}

// Iteration 0: out = img. 4px-wide strips, all global I/O 16B. (round-4 verbatim)
__global__ __launch_bounds__(256, 4) void tv_step0(
    const float* __restrict__ img, const float* __restrict__ weight,
    __half* __restrict__ imgh, uint32_t* __restrict__ ptout,
    float* __restrict__ pn)
{
    const int im = blockIdx.z;
    const int bid = blockIdx.y * 8 + blockIdx.x;
    const float w = weight[im / CCH];
    const int x0 = blockIdx.x * 64, y0 = blockIdx.y * 64;
    const float* imgI = img + (size_t)im * HH * WW;
    __half* hI = imgh + (size_t)im * HH * WW;
    uint32_t* pI = ptout + (size_t)im * HH * WW;
    __shared__ float s[65][68];
    const int tid = threadIdx.x;
    const int tx = tid & 15, ry = tid >> 4;
    const int gx = x0 + 4 * tx;

    float o[4][4];
    #pragma unroll
    for (int i = 0; i < 4; ++i) {
        int ey = ry + 16 * i, gy = y0 + ey;
        float4 v = *(const float4*)(imgI + (size_t)gy * WW + gx);
        o[i][0] = v.x; o[i][1] = v.y; o[i][2] = v.z; o[i][3] = v.w;
        *(float4*)&s[ey][4 * tx] = v;
    }
    if (tx == 15 && x0 + 64 < WW) {
        #pragma unroll
        for (int i = 0; i < 4; ++i) {
            int ey = ry + 16 * i, gy = y0 + ey;
            s[ey][64] = imgI[(size_t)gy * WW + x0 + 64];
        }
    }
    if (ry == 0 && y0 + 64 < HH) {
        *(float4*)&s[64][4 * tx] = *(const float4*)(imgI + (size_t)(y0 + 64) * WW + gx);
    }
    __syncthreads();

    float accn = 0.f;
    const float tw = TAU / w;
    #pragma unroll
    for (int i = 0; i < 4; ++i) {
        int ey = ry + 16 * i, gy = y0 + ey;
        float4 dn = *(float4*)&s[ey + 1][4 * tx];
        float rt_sh = __shfl_down(o[i][0], 1, 64);
        float rt = (tx == 15) ? s[ey][64] : rt_sh;
        float dnv[4] = {dn.x, dn.y, dn.z, dn.w};
        uint32_t pv[4];
        #pragma unroll
        for (int j = 0; j < 4; ++j) {
            float ov = o[i][j];
            float g0 = (gy < HH - 1) ? dnv[j] - ov : 0.f;
            float rn = (j < 3) ? o[i][j + 1] : rt;
            float g1 = (gx + j < WW - 1) ? rn - ov : 0.f;
            float ss2 = g0 * g0 + g1 * g1;
            float nrm = (ss2 > 0.f) ? sqrtf(ss2) : 0.f;
            accn += nrm;
            float inv = __builtin_amdgcn_rcpf(1.f + tw * nrm);
            pv[j] = f2h2(-TAU * g0 * inv, -TAU * g1 * inv);
        }
        size_t off = (size_t)gy * WW + gx;
        *(uint4*)(pI + off) = make_uint4(pv[0], pv[1], pv[2], pv[3]);
        *(uint2*)(hI + off) = make_uint2(f2h2(o[i][0], o[i][1]), f2h2(o[i][2], o[i][3]));
    }
    block_reduce_store1(accn, &pn[im * 64 + bid], tid);
}

// Iterations 1..8 — register-tile, 64 wide x 128 tall per block (8 rows/thread).
// Grid 8x4x24 = 768 blocks = 3/CU co-resident (one scheduling phase).
__global__ __launch_bounds__(256, 4) void tv_stepN(
    int it,
    const __half* __restrict__ imgh, const float* __restrict__ weight,
    const uint32_t* __restrict__ pt_in, uint32_t* __restrict__ pt_out,
    float* __restrict__ sc, float* __restrict__ pd, float* __restrict__ pn)
{
    const int im = blockIdx.z;
    const int bid = blockIdx.y * 8 + blockIdx.x;   // 0..31
    const int tid = threadIdx.x;
    const float w = weight[im / CCH];

    // --- replay head: derive S_{it-1}. it==1 consumes step0's 64 partials;
    //     it>=2 consumes stepN's 32 partials (lanes 32..63 contribute 0).
    __shared__ int sh_done;
    {
        const int slot = (it - 1) & 1;
        if (tid < 64) {
            float d = 0.f, n = 0.f;
            if (it == 1) {
                n = pn[(slot * NIMG + im) * 64 + tid];
            } else if (tid < 32) {
                d = pd[(slot * NIMG + im) * 64 + tid];
                n = pn[(slot * NIMG + im) * 64 + tid];
            }
            for (int off = 32; off > 0; off >>= 1) {
                d += __shfl_down(d, off, 64);
                n += __shfl_down(n, off, 64);
            }
            if (tid == 0) {
                float Eprev, Einit; int done, lastk;
                if (it == 1) {
                    float E0 = w * n / NUMEL;
                    Eprev = E0; Einit = E0; done = 0; lastk = 0;
                } else {
                    const float* sIn = sc + slot * 96;
                    Eprev = sIn[im]; Einit = sIn[24 + im];
                    done = ((const int*)sIn)[48 + im];
                    lastk = ((const int*)sIn)[72 + im];
                    if (!done) {
                        float Et = (d + w * n) / NUMEL;
                        if (fabsf(Eprev - Et) < TVEPS * Einit) { done = 1; lastk = it - 1; }
                        Eprev = Et;
                    }
                }
                if (bid == 0) {
                    float* sOut = sc + (it & 1) * 96;
                    sOut[im] = Eprev; sOut[24 + im] = Einit;
                    ((int*)sOut)[48 + im] = done;
                    ((int*)sOut)[72 + im] = lastk;
                }
                sh_done = done;
            }
        }
    }
    __syncthreads();
    if (sh_done) return;

    const int x0 = blockIdx.x * 64, y0 = blockIdx.y * 128;
    const __half* hI = imgh + (size_t)im * HH * WW;
    const uint32_t* pinI = pt_in + (size_t)im * HH * WW;
    uint32_t* poutI = pt_out + (size_t)im * HH * WW;
    const int tx = tid & 15, ty = tid >> 4;
    const int gx = x0 + 4 * tx;
    const int gy0 = y0 + 8 * ty;
    const float tw = TAU / w;

    __shared__ uint4  XP[16][16];   // pt row 7 of each band
    __shared__ float4 XO[16][16];   // out row 0 of each band

    // ---- loads: own 8 rows of pt + imgh ----
    uint4 c[8]; uint2 ih[8];
    #pragma unroll
    for (int i = 0; i < 8; ++i) {
        size_t off = (size_t)(gy0 + i) * WW + gx;
        c[i] = *(const uint4*)(pinI + off);
        ih[i] = *(const uint2*)(hI + off);
    }
    XP[ty][tx] = c[7];

    // halos (edge threads only)
    uint32_t lf[8] = {0u, 0u, 0u, 0u, 0u, 0u, 0u, 0u};
    if (tx == 0 && x0 > 0) {
        #pragma unroll
        for (int i = 0; i < 8; ++i) lf[i] = pinI[(size_t)(gy0 + i) * WW + x0 - 1];
    }
    uint4 upg = make_uint4(0u, 0u, 0u, 0u);
    if (ty == 0 && y0 > 0) upg = *(const uint4*)(pinI + (size_t)(y0 - 1) * WW + gx);

    uint32_t ep[9] = {0u, 0u, 0u, 0u, 0u, 0u, 0u, 0u, 0u};
    float ihE[8] = {0.f, 0.f, 0.f, 0.f, 0.f, 0.f, 0.f, 0.f};
    const bool hasE = (tx == 15) && (x0 + 64 < WW);
    if (hasE) {
        const int xe = x0 + 64;
        ep[0] = (gy0 > 0) ? pinI[(size_t)(gy0 - 1) * WW + xe] : 0u;
        #pragma unroll
        for (int i = 0; i < 8; ++i) {
            ep[i + 1] = pinI[(size_t)(gy0 + i) * WW + xe];
            ihE[i] = __half2float(hI[(size_t)(gy0 + i) * WW + xe]);
        }
    }
    uint4 sp = make_uint4(0u, 0u, 0u, 0u); uint2 ihS = make_uint2(0u, 0u);
    uint32_t spl = 0u;
    const bool hasS = (ty == 15) && (y0 + 128 < HH);
    if (hasS) {
        size_t off = (size_t)(y0 + 128) * WW + gx;
        sp = *(const uint4*)(pinI + off);
        ihS = *(const uint2*)(hI + off);
        if (tx == 0 && x0 > 0) spl = pinI[(size_t)(y0 + 128) * WW + x0 - 1];
    }
    __syncthreads();

    // ---- OUT phase: o = img_h + div(pt_in) ----
    uint4 up4 = (ty > 0) ? XP[ty - 1][tx] : upg;
    float o[8][4];
    float accd = 0.f;
    {
        uint32_t ua[4] = {up4.x, up4.y, up4.z, up4.w};
        #pragma unroll
        for (int i = 0; i < 8; ++i) {
            uint32_t ca[4] = {c[i].x, c[i].y, c[i].z, c[i].w};
            uint32_t lsh = __shfl_up(c[i].w, 1, 64);
            uint32_t lw = (tx > 0) ? lsh : lf[i];
            uint32_t cu[4];
            if (i > 0) {
                cu[0] = (&c[i - 1].x)[0]; cu[1] = (&c[i - 1].x)[1];
                cu[2] = (&c[i - 1].x)[2]; cu[3] = (&c[i - 1].x)[3];
            } else {
                cu[0] = ua[0]; cu[1] = ua[1]; cu[2] = ua[2]; cu[3] = ua[3];
            }
            float imv[4]; h4_to_f(ih[i], imv);
            #pragma unroll
            for (int j = 0; j < 4; ++j) {
                float2 cf = h2f(ca[j]);
                float up = h2f(cu[j]).x;
                float le = (j > 0) ? h2f(ca[j - 1]).y : h2f(lw).y;
                float dv = -(cf.x + cf.y) + up + le;
                o[i][j] = imv[j] + dv;
                accd += dv * dv;
            }
        }
    }

    // halo-out: east col (x0+64), own 8 rows
    float he[8] = {0.f, 0.f, 0.f, 0.f, 0.f, 0.f, 0.f, 0.f};
    if (hasE) {
        uint32_t prev = ep[0];
        #pragma unroll
        for (int i = 0; i < 8; ++i) {
            float2 cf = h2f(ep[i + 1]);
            float up = h2f(prev).x;
            float le = h2f(c[i].w).y;
            he[i] = ihE[i] + (-(cf.x + cf.y) + up + le);
            prev = ep[i + 1];
        }
    }
    // halo-out: south row (y0+128)
    float hs[4] = {0.f, 0.f, 0.f, 0.f};
    if (hasS) {
        uint32_t ssh = __shfl_up(sp.w, 1, 64);
        uint32_t sl = (tx > 0) ? ssh : spl;
        uint32_t sa[4] = {sp.x, sp.y, sp.z, sp.w};
        uint32_t c7[4] = {c[7].x, c[7].y, c[7].z, c[7].w};
        float smv[4]; h4_to_f(ihS, smv);
        #pragma unroll
        for (int j = 0; j < 4; ++j) {
            float2 cf = h2f(sa[j]);
            float up = h2f(c7[j]).x;
            float le = (j > 0) ? h2f(sa[j - 1]).y : h2f(sl).y;
            hs[j] = smv[j] + (-(cf.x + cf.y) + up + le);
        }
    }

    XO[ty][tx] = make_float4(o[0][0], o[0][1], o[0][2], o[0][3]);
    __syncthreads();

    // ---- PT phase: gradients of out, pt update ----
    float bel4[4];
    if (ty < 15) {
        float4 t = XO[ty + 1][tx];
        bel4[0] = t.x; bel4[1] = t.y; bel4[2] = t.z; bel4[3] = t.w;
    } else {
        bel4[0] = hs[0]; bel4[1] = hs[1]; bel4[2] = hs[2]; bel4[3] = hs[3];
    }
    float accn = 0.f;
    #pragma unroll
    for (int i = 0; i < 8; ++i) {
        int gy = gy0 + i;
        float esh = __shfl_down(o[i][0], 1, 64);
        float rt = (tx < 15) ? esh : he[i];
        uint32_t ca[4] = {c[i].x, c[i].y, c[i].z, c[i].w};
        uint32_t pv[4];
        #pragma unroll
        for (int j = 0; j < 4; ++j) {
            float ov = o[i][j];
            float below = (i < 7) ? o[i + 1][j] : bel4[j];
            float g0 = (gy < HH - 1) ? below - ov : 0.f;
            float rn = (j < 3) ? o[i][j + 1] : rt;
            float g1 = (gx + j < WW - 1) ? rn - ov : 0.f;
            float ss2 = g0 * g0 + g1 * g1;
            float nrm = (ss2 > 0.f) ? sqrtf(ss2) : 0.f;
            accn += nrm;
            float inv = __builtin_amdgcn_rcpf(1.f + tw * nrm);
            float2 cf = h2f(ca[j]);
            pv[j] = f2h2((cf.x - TAU * g0) * inv, (cf.y - TAU * g1) * inv);
        }
        *(uint4*)(poutI + (size_t)gy * WW + gx) = make_uint4(pv[0], pv[1], pv[2], pv[3]);
    }

    block_reduce_store(accd, accn,
                       &pd[((it & 1) * NIMG + im) * 64 + bid],
                       &pn[((it & 1) * NIMG + im) * 64 + bid], tid);
}

// Epilogue: out = img(fp32) + div(pt of last executed step's input).
// (round-4 verbatim except 32-entry partial guard)
__global__ __launch_bounds__(256, 4) void tv_out(
    const float* __restrict__ img, float* __restrict__ out,
    const uint32_t* __restrict__ ptA, const uint32_t* __restrict__ ptB,
    const float* __restrict__ weight, const float* __restrict__ sc,
    const float* __restrict__ pd, const float* __restrict__ pn)
{
    const int im = blockIdx.z;
    const int tid = threadIdx.x;
    const float w = weight[im / CCH];
    __shared__ int2 shk;
    if (tid < 64) {
        const float* sIn = sc;  // slot 0 holds S_7 after it=8
        int done = ((const int*)sIn)[48 + im];
        int lastk = ((const int*)sIn)[72 + im];
        if (!done) {
            float d = 0.f, n = 0.f;
            if (tid < 32) {            // it=8 wrote 32 partials/image
                d = pd[im * 64 + tid];
                n = pn[im * 64 + tid];
            }
            for (int off = 32; off > 0; off >>= 1) {
                d += __shfl_down(d, off, 64);
                n += __shfl_down(n, off, 64);
            }
            if (tid == 0) {
                float Et = (d + w * n) / NUMEL;
                if (fabsf(sIn[im] - Et) < TVEPS * sIn[24 + im]) { done = 1; lastk = 8; }
            }
        }
        if (tid == 0) { shk.x = done; shk.y = lastk; }
    }
    __syncthreads();
    int k = shk.x ? shk.y : (NITER - 1);
    const uint32_t* p = ((((k - 1) & 1) == 0) ? ptA : ptB) + (size_t)im * HH * WW;
    const float* imgI = img + (size_t)im * HH * WW;
    float* outI = out + (size_t)im * HH * WW;
    const int x0 = blockIdx.x * 64, y0 = blockIdx.y * 64;
    const int tx = tid & 15, ry = tid >> 4;
    const int gx = x0 + 4 * tx;
    #pragma unroll
    for (int i = 0; i < 4; ++i) {
        int gy = y0 + ry + 16 * i;
        size_t off = (size_t)gy * WW + gx;
        uint4 cv = *(const uint4*)(p + off);
        uint4 uv = make_uint4(0u, 0u, 0u, 0u);
        if (gy > 0) uv = *(const uint4*)(p + off - WW);
        uint32_t lfv = (gx > 0) ? p[off - 1] : 0u;
        float4 iv = *(const float4*)(imgI + off);
        uint32_t cc[4] = {cv.x, cv.y, cv.z, cv.w};
        uint32_t uu[4] = {uv.x, uv.y, uv.z, uv.w};
        uint32_t lt[4] = {lfv, cv.x, cv.y, cv.z};
        float ivv[4] = {iv.x, iv.y, iv.z, iv.w};
        float r[4];
        #pragma unroll
        for (int j = 0; j < 4; ++j) {
            float2 cf = h2f(cc[j]);
            r[j] = ivv[j] + (-(cf.x + cf.y) + h2f(uu[j]).x + h2f(lt[j]).y);
        }
        *(float4*)(outI + off) = make_float4(r[0], r[1], r[2], r[3]);
    }
}

extern "C" void kernel_launch(void* const* d_in, const int* in_sizes, int n_in,
                              void* d_out, int out_size, void* d_ws, size_t ws_size,
                              hipStream_t stream)
{
    const float* img = (const float*)d_in[0];
    const float* weight = (const float*)d_in[1];
    float* out = (float*)d_out;
    float* sc = (float*)d_ws;
    float* pd = (float*)((char*)d_ws + 4096);
    float* pn = (float*)((char*)d_ws + 16384);
    __half* imgh = (__half*)((char*)d_ws + 32768);
    uint32_t* ptA = (uint32_t*)((char*)d_ws + 12615680);
    uint32_t* ptB = (uint32_t*)((char*)d_ws + 37781504);

    dim3 block(256);

    tv_step0<<<dim3(8, 8, NIMG), block, 0, stream>>>(img, weight, imgh, ptA, pn);

    // 768-block stepN: 64x128 tiles, exactly 3 blocks/CU co-resident.
    for (int it = 1; it <= 8; ++it) {
        uint32_t* pin  = (((it - 1) & 1) == 0) ? ptA : ptB;
        uint32_t* pout = ((it & 1) == 0) ? ptA : ptB;
        tv_stepN<<<dim3(8, 4, NIMG), block, 0, stream>>>(it, imgh, weight, pin, pout, sc, pd, pn);
    }
    tv_out<<<dim3(8, 8, NIMG), block, 0, stream>>>(img, out, ptA, ptB, weight, sc, pd, pn);
}

// Round 7
// 236.889 us; speedup vs baseline: 1.1893x; 1.1893x over previous
//
#include <hip/hip_runtime.h>
#include <hip/hip_fp16.h>
#include <math.h>
#include <stdint.h>

#define HH 512
#define WW 512
#define NIMG 24
#define CCH 3
#define TAU 0.25f
#define TVEPS 2e-4f
#define NUMEL 262144.0f
#define NITER 10

// ws layout (256 MiB):
//   byte 0     : sc — 2 slots x 96 floats, slot s at sc+96*s:
//                [0..23]=E_prev, [24..47]=E_init, int[48..71]=done, int[72..95]=last_k
//   byte 4096  : pd [2][NIMG][64]  (slot = it&1)
//   byte 16384 : pn [2][NIMG][64]
//   byte 32768 : imgh (__half, 24*512*512)
//   byte 12615680 : ptA (uint32 packed half2)
//   byte 37781504 : ptB

__device__ __forceinline__ float2 h2f(uint32_t v) {
    __half2 h; *reinterpret_cast<uint32_t*>(&h) = v;
    return __half22float2(h);
}
__device__ __forceinline__ uint32_t f2h2(float a, float b) {
    __half2 h = __floats2half2_rn(a, b);
    return *reinterpret_cast<uint32_t*>(&h);
}
__device__ __forceinline__ void h4_to_f(uint2 hv, float* f) {
    float2 a = h2f(hv.x), b = h2f(hv.y);
    f[0] = a.x; f[1] = a.y; f[2] = b.x; f[3] = b.y;
}

__device__ __forceinline__ void block_reduce_store(float v0, float v1,
                                                   float* p0, float* p1, int tid) {
    for (int off = 32; off > 0; off >>= 1) {
        v0 += __shfl_down(v0, off, 64);
        v1 += __shfl_down(v1, off, 64);
    }
    __shared__ float sr[2][4];
    int wave = tid >> 6, lane = tid & 63;
    if (lane == 0) { sr[0][wave] = v0; sr[1][wave] = v1; }
    __syncthreads();
    if (tid == 0) {
        *p0 = (sr[0][0] + sr[0][1]) + (sr[0][2] + sr[0][3]);
        *p1 = (sr[1][0] + sr[1][1]) + (sr[1][2] + sr[1][3]);
    }
}

__device__ __forceinline__ void block_reduce_store1(float v, float* p, int tid) {
    for (int off = 32; off > 0; off >>= 1) v += __shfl_down(v, off, 64);
    __shared__ float sr[4];
    if ((tid & 63) == 0) sr[tid >> 6] = v;
    __syncthreads();
    if (tid == 0) *p = (sr[0] + sr[1]) + (sr[2] + sr[3]);
}

// Iteration 0: out = img. (round-4 verbatim)
__global__ __launch_bounds__(256, 4) void tv_step0(
    const float* __restrict__ img, const float* __restrict__ weight,
    __half* __restrict__ imgh, uint32_t* __restrict__ ptout,
    float* __restrict__ pn)
{
    const int im = blockIdx.z;
    const int bid = blockIdx.y * 8 + blockIdx.x;
    const float w = weight[im / CCH];
    const int x0 = blockIdx.x * 64, y0 = blockIdx.y * 64;
    const float* imgI = img + (size_t)im * HH * WW;
    __half* hI = imgh + (size_t)im * HH * WW;
    uint32_t* pI = ptout + (size_t)im * HH * WW;
    __shared__ float s[65][68];
    const int tid = threadIdx.x;
    const int tx = tid & 15, ry = tid >> 4;
    const int gx = x0 + 4 * tx;

    float o[4][4];
    #pragma unroll
    for (int i = 0; i < 4; ++i) {
        int ey = ry + 16 * i, gy = y0 + ey;
        float4 v = *(const float4*)(imgI + (size_t)gy * WW + gx);
        o[i][0] = v.x; o[i][1] = v.y; o[i][2] = v.z; o[i][3] = v.w;
        *(float4*)&s[ey][4 * tx] = v;
    }
    if (tx == 15 && x0 + 64 < WW) {
        #pragma unroll
        for (int i = 0; i < 4; ++i) {
            int ey = ry + 16 * i, gy = y0 + ey;
            s[ey][64] = imgI[(size_t)gy * WW + x0 + 64];
        }
    }
    if (ry == 0 && y0 + 64 < HH) {
        *(float4*)&s[64][4 * tx] = *(const float4*)(imgI + (size_t)(y0 + 64) * WW + gx);
    }
    __syncthreads();

    float accn = 0.f;
    const float tw = TAU / w;
    #pragma unroll
    for (int i = 0; i < 4; ++i) {
        int ey = ry + 16 * i, gy = y0 + ey;
        float4 dn = *(float4*)&s[ey + 1][4 * tx];
        float rt_sh = __shfl_down(o[i][0], 1, 64);
        float rt = (tx == 15) ? s[ey][64] : rt_sh;
        float dnv[4] = {dn.x, dn.y, dn.z, dn.w};
        uint32_t pv[4];
        #pragma unroll
        for (int j = 0; j < 4; ++j) {
            float ov = o[i][j];
            float g0 = (gy < HH - 1) ? dnv[j] - ov : 0.f;
            float rn = (j < 3) ? o[i][j + 1] : rt;
            float g1 = (gx + j < WW - 1) ? rn - ov : 0.f;
            float ss2 = g0 * g0 + g1 * g1;
            float nrm = (ss2 > 0.f) ? sqrtf(ss2) : 0.f;
            accn += nrm;
            float inv = __builtin_amdgcn_rcpf(1.f + tw * nrm);
            pv[j] = f2h2(-TAU * g0 * inv, -TAU * g1 * inv);
        }
        size_t off = (size_t)gy * WW + gx;
        *(uint4*)(pI + off) = make_uint4(pv[0], pv[1], pv[2], pv[3]);
        *(uint2*)(hI + off) = make_uint2(f2h2(o[i][0], o[i][1]), f2h2(o[i][2], o[i][3]));
    }
    block_reduce_store1(accn, &pn[im * 64 + bid], tid);
}

// Iterations 1..8 — register-tile 64x64 (round-4 structure) with:
//  (a) tile/halo loads issued BEFORE the replay head (latency overlap),
//  (b) pt pre-converted to float planes px/py (one cvt per value).
__global__ __launch_bounds__(256, 4) void tv_stepN(
    int it,
    const __half* __restrict__ imgh, const float* __restrict__ weight,
    const uint32_t* __restrict__ pt_in, uint32_t* __restrict__ pt_out,
    float* __restrict__ sc, float* __restrict__ pd, float* __restrict__ pn)
{
    const int im = blockIdx.z;
    const int bid = blockIdx.y * 8 + blockIdx.x;
    const int tid = threadIdx.x;
    const float w = weight[im / CCH];
    const int x0 = blockIdx.x * 64, y0 = blockIdx.y * 64;
    const __half* hI = imgh + (size_t)im * HH * WW;
    const uint32_t* pinI = pt_in + (size_t)im * HH * WW;
    uint32_t* poutI = pt_out + (size_t)im * HH * WW;
    const int tx = tid & 15, ty = tid >> 4;
    const int gx = x0 + 4 * tx;
    const int gy0 = y0 + 4 * ty;
    const float tw = TAU / w;

    // ---- (a) issue ALL tile + halo loads first ----
    uint4 c[4]; uint2 ih[4];
    #pragma unroll
    for (int i = 0; i < 4; ++i) {
        size_t off = (size_t)(gy0 + i) * WW + gx;
        c[i] = *(const uint4*)(pinI + off);
        ih[i] = *(const uint2*)(hI + off);
    }
    uint32_t lf[4] = {0u, 0u, 0u, 0u};
    if (tx == 0 && x0 > 0) {
        #pragma unroll
        for (int i = 0; i < 4; ++i) lf[i] = pinI[(size_t)(gy0 + i) * WW + x0 - 1];
    }
    uint4 upg = make_uint4(0u, 0u, 0u, 0u);
    if (ty == 0 && y0 > 0) upg = *(const uint4*)(pinI + (size_t)(y0 - 1) * WW + gx);

    uint32_t ep[5] = {0u, 0u, 0u, 0u, 0u};
    float ihE[4] = {0.f, 0.f, 0.f, 0.f};
    const bool hasE = (tx == 15) && (x0 + 64 < WW);
    if (hasE) {
        const int xe = x0 + 64;
        ep[0] = (gy0 > 0) ? pinI[(size_t)(gy0 - 1) * WW + xe] : 0u;
        #pragma unroll
        for (int i = 0; i < 4; ++i) {
            ep[i + 1] = pinI[(size_t)(gy0 + i) * WW + xe];
            ihE[i] = __half2float(hI[(size_t)(gy0 + i) * WW + xe]);
        }
    }
    uint4 sp = make_uint4(0u, 0u, 0u, 0u); uint2 ihS = make_uint2(0u, 0u);
    uint32_t spl = 0u;
    const bool hasS = (ty == 15) && (y0 + 64 < HH);
    if (hasS) {
        size_t off = (size_t)(y0 + 64) * WW + gx;
        sp = *(const uint4*)(pinI + off);
        ihS = *(const uint2*)(hI + off);
        if (tx == 0 && x0 > 0) spl = pinI[(size_t)(y0 + 64) * WW + x0 - 1];
    }

    // ---- replay head: derive S_{it-1} (round-4 verbatim; overlaps load latency) ----
    __shared__ int sh_done;
    {
        const int slot = (it - 1) & 1;
        if (tid < 64) {
            float d = 0.f, n = pn[(slot * NIMG + im) * 64 + tid];
            if (it > 1) d = pd[(slot * NIMG + im) * 64 + tid];
            for (int off = 32; off > 0; off >>= 1) {
                d += __shfl_down(d, off, 64);
                n += __shfl_down(n, off, 64);
            }
            if (tid == 0) {
                float Eprev, Einit; int done, lastk;
                if (it == 1) {
                    float E0 = w * n / NUMEL;
                    Eprev = E0; Einit = E0; done = 0; lastk = 0;
                } else {
                    const float* sIn = sc + slot * 96;
                    Eprev = sIn[im]; Einit = sIn[24 + im];
                    done = ((const int*)sIn)[48 + im];
                    lastk = ((const int*)sIn)[72 + im];
                    if (!done) {
                        float Et = (d + w * n) / NUMEL;
                        if (fabsf(Eprev - Et) < TVEPS * Einit) { done = 1; lastk = it - 1; }
                        Eprev = Et;
                    }
                }
                if (bid == 0) {
                    float* sOut = sc + (it & 1) * 96;
                    sOut[im] = Eprev; sOut[24 + im] = Einit;
                    ((int*)sOut)[48 + im] = done;
                    ((int*)sOut)[72 + im] = lastk;
                }
                sh_done = done;
            }
        }
    }
    __syncthreads();
    if (sh_done) return;

    __shared__ uint4  XP[16][16];   // pt row 3 of each band (packed)
    __shared__ float4 XO[16][16];   // out row 0 of each band

    XP[ty][tx] = c[3];

    // ---- (b) pre-convert pt to float planes (exact; c dies here) ----
    float px[4][4], py[4][4];
    #pragma unroll
    for (int i = 0; i < 4; ++i) {
        uint32_t ca[4] = {c[i].x, c[i].y, c[i].z, c[i].w};
        #pragma unroll
        for (int j = 0; j < 4; ++j) {
            float2 f = h2f(ca[j]);
            px[i][j] = f.x; py[i][j] = f.y;
        }
    }
    __syncthreads();

    // ---- OUT phase: o = img_h + div(pt_in) ----
    float o[4][4];
    float accd = 0.f;
    {
        uint4 up4 = (ty > 0) ? XP[ty - 1][tx] : upg;
        uint32_t ua[4] = {up4.x, up4.y, up4.z, up4.w};
        float upx[4];
        #pragma unroll
        for (int j = 0; j < 4; ++j) upx[j] = h2f(ua[j]).x;
        #pragma unroll
        for (int i = 0; i < 4; ++i) {
            float lsh = __shfl_up(py[i][3], 1, 64);
            float le0 = (tx > 0) ? lsh : h2f(lf[i]).y;
            float imv[4]; h4_to_f(ih[i], imv);
            #pragma unroll
            for (int j = 0; j < 4; ++j) {
                float up = (i > 0) ? px[i - 1][j] : upx[j];
                float le = (j > 0) ? py[i][j - 1] : le0;
                float dv = -(px[i][j] + py[i][j]) + up + le;
                o[i][j] = imv[j] + dv;
                accd += dv * dv;
            }
        }
    }

    // halo-out: east col (x0+64)
    float he[4] = {0.f, 0.f, 0.f, 0.f};
    if (hasE) {
        uint32_t prev = ep[0];
        #pragma unroll
        for (int i = 0; i < 4; ++i) {
            float2 cf = h2f(ep[i + 1]);
            float up = h2f(prev).x;
            float le = py[i][3];
            he[i] = ihE[i] + (-(cf.x + cf.y) + up + le);
            prev = ep[i + 1];
        }
    }
    // halo-out: south row (y0+64)
    float hs[4] = {0.f, 0.f, 0.f, 0.f};
    if (hasS) {
        uint32_t ssh = __shfl_up(sp.w, 1, 64);
        uint32_t sl = (tx > 0) ? ssh : spl;
        uint32_t sa[4] = {sp.x, sp.y, sp.z, sp.w};
        float smv[4]; h4_to_f(ihS, smv);
        #pragma unroll
        for (int j = 0; j < 4; ++j) {
            float2 cf = h2f(sa[j]);
            float up = px[3][j];
            float le = (j > 0) ? h2f(sa[j - 1]).y : h2f(sl).y;
            hs[j] = smv[j] + (-(cf.x + cf.y) + up + le);
        }
    }

    XO[ty][tx] = make_float4(o[0][0], o[0][1], o[0][2], o[0][3]);
    __syncthreads();

    // ---- PT phase: gradients of out, pt update ----
    float bel4[4];
    if (ty < 15) {
        float4 t = XO[ty + 1][tx];
        bel4[0] = t.x; bel4[1] = t.y; bel4[2] = t.z; bel4[3] = t.w;
    } else {
        bel4[0] = hs[0]; bel4[1] = hs[1]; bel4[2] = hs[2]; bel4[3] = hs[3];
    }
    float accn = 0.f;
    #pragma unroll
    for (int i = 0; i < 4; ++i) {
        int gy = gy0 + i;
        float esh = __shfl_down(o[i][0], 1, 64);
        float rt = (tx < 15) ? esh : he[i];
        uint32_t pv[4];
        #pragma unroll
        for (int j = 0; j < 4; ++j) {
            float ov = o[i][j];
            float below = (i < 3) ? o[i + 1][j] : bel4[j];
            float g0 = (gy < HH - 1) ? below - ov : 0.f;
            float rn = (j < 3) ? o[i][j + 1] : rt;
            float g1 = (gx + j < WW - 1) ? rn - ov : 0.f;
            float ss2 = g0 * g0 + g1 * g1;
            float nrm = (ss2 > 0.f) ? sqrtf(ss2) : 0.f;
            accn += nrm;
            float inv = __builtin_amdgcn_rcpf(1.f + tw * nrm);
            pv[j] = f2h2((px[i][j] - TAU * g0) * inv, (py[i][j] - TAU * g1) * inv);
        }
        *(uint4*)(poutI + (size_t)gy * WW + gx) = make_uint4(pv[0], pv[1], pv[2], pv[3]);
    }

    block_reduce_store(accd, accn,
                       &pd[((it & 1) * NIMG + im) * 64 + bid],
                       &pn[((it & 1) * NIMG + im) * 64 + bid], tid);
}

// Epilogue (round-4 logic; img loads hoisted above the head).
__global__ __launch_bounds__(256, 4) void tv_out(
    const float* __restrict__ img, float* __restrict__ out,
    const uint32_t* __restrict__ ptA, const uint32_t* __restrict__ ptB,
    const float* __restrict__ weight, const float* __restrict__ sc,
    const float* __restrict__ pd, const float* __restrict__ pn)
{
    const int im = blockIdx.z;
    const int tid = threadIdx.x;
    const float w = weight[im / CCH];
    const float* imgI = img + (size_t)im * HH * WW;
    float* outI = out + (size_t)im * HH * WW;
    const int x0 = blockIdx.x * 64, y0 = blockIdx.y * 64;
    const int tx = tid & 15, ry = tid >> 4;
    const int gx = x0 + 4 * tx;

    // hoisted img loads (k-independent)
    float4 iv4[4];
    #pragma unroll
    for (int i = 0; i < 4; ++i) {
        int gy = y0 + ry + 16 * i;
        iv4[i] = *(const float4*)(imgI + (size_t)gy * WW + gx);
    }

    __shared__ int2 shk;
    if (tid < 64) {
        const float* sIn = sc;  // slot 0 holds S_7 after it=8
        int done = ((const int*)sIn)[48 + im];
        int lastk = ((const int*)sIn)[72 + im];
        if (!done) {
            float d = pd[im * 64 + tid];   // slot 0 = it 8's partials
            float n = pn[im * 64 + tid];
            for (int off = 32; off > 0; off >>= 1) {
                d += __shfl_down(d, off, 64);
                n += __shfl_down(n, off, 64);
            }
            if (tid == 0) {
                float Et = (d + w * n) / NUMEL;
                if (fabsf(sIn[im] - Et) < TVEPS * sIn[24 + im]) { done = 1; lastk = 8; }
            }
        }
        if (tid == 0) { shk.x = done; shk.y = lastk; }
    }
    __syncthreads();
    int k = shk.x ? shk.y : (NITER - 1);
    const uint32_t* p = ((((k - 1) & 1) == 0) ? ptA : ptB) + (size_t)im * HH * WW;
    #pragma unroll
    for (int i = 0; i < 4; ++i) {
        int gy = y0 + ry + 16 * i;
        size_t off = (size_t)gy * WW + gx;
        uint4 cv = *(const uint4*)(p + off);
        uint4 uv = make_uint4(0u, 0u, 0u, 0u);
        if (gy > 0) uv = *(const uint4*)(p + off - WW);
        uint32_t lfv = (gx > 0) ? p[off - 1] : 0u;
        uint32_t cc[4] = {cv.x, cv.y, cv.z, cv.w};
        uint32_t uu[4] = {uv.x, uv.y, uv.z, uv.w};
        uint32_t lt[4] = {lfv, cv.x, cv.y, cv.z};
        float ivv[4] = {iv4[i].x, iv4[i].y, iv4[i].z, iv4[i].w};
        float r[4];
        #pragma unroll
        for (int j = 0; j < 4; ++j) {
            float2 cf = h2f(cc[j]);
            r[j] = ivv[j] + (-(cf.x + cf.y) + h2f(uu[j]).x + h2f(lt[j]).y);
        }
        *(float4*)(outI + off) = make_float4(r[0], r[1], r[2], r[3]);
    }
}

extern "C" void kernel_launch(void* const* d_in, const int* in_sizes, int n_in,
                              void* d_out, int out_size, void* d_ws, size_t ws_size,
                              hipStream_t stream)
{
    const float* img = (const float*)d_in[0];
    const float* weight = (const float*)d_in[1];
    float* out = (float*)d_out;
    float* sc = (float*)d_ws;
    float* pd = (float*)((char*)d_ws + 4096);
    float* pn = (float*)((char*)d_ws + 16384);
    __half* imgh = (__half*)((char*)d_ws + 32768);
    uint32_t* ptA = (uint32_t*)((char*)d_ws + 12615680);
    uint32_t* ptB = (uint32_t*)((char*)d_ws + 37781504);

    dim3 grid(8, 8, NIMG);
    dim3 block(256);

    tv_step0<<<grid, block, 0, stream>>>(img, weight, imgh, ptA, pn);
    for (int it = 1; it <= 8; ++it) {
        uint32_t* pin  = (((it - 1) & 1) == 0) ? ptA : ptB;
        uint32_t* pout = ((it & 1) == 0) ? ptA : ptB;
        tv_stepN<<<grid, block, 0, stream>>>(it, imgh, weight, pin, pout, sc, pd, pn);
    }
    tv_out<<<grid, block, 0, stream>>>(img, out, ptA, ptB, weight, sc, pd, pn);
}